// Round 3
// baseline (383.558 us; speedup 1.0000x reference)
//
#include <hip/hip_runtime.h>
#include <math.h>

typedef __attribute__((ext_vector_type(2))) float f32x2;
typedef __attribute__((ext_vector_type(4))) float f32x4;

// Problem dims (fixed): (B=4, 1, D=160, H=192, W=192) f32
#define BDIM 4
#define DDIM 160
#define HDIM 192
#define WDIM 192
#define NTOT (BDIM * DDIM * HDIM * WDIM)

#define TH 16
#define TW 64
#define SEG 20               // output D-slices per block
#define NS  (SEG + 6)        // 26 input slices
#define NTH 512

#define RHH (TH + 6)         // 22
#define RWW (TW + 6)         // 70
#define NRAW (RHH * RWW)     // 1540

template<int N> struct IC { static constexpr int v = N; };

__device__ __forceinline__ float rcp_fast(float x) {
#if __has_builtin(__builtin_amdgcn_rcpf)
    return __builtin_amdgcn_rcpf(x);
#else
    return 1.0f / x;
#endif
}

__global__ __launch_bounds__(NTH, 4)
void nq_main(const float* __restrict__ X,   // recon
             const float* __restrict__ Y,   // target
             float* __restrict__ acc)       // [0]=ssim_sum [1]=l1_num [2]=l1_den
{
    constexpr float Gc[7] = {
        0.03663285f, 0.11128076f, 0.21674532f, 0.27068215f,
        0.21674532f, 0.11128076f, 0.03663285f };
    constexpr float C1f = 4.0e-4f;   // (0.01*2)^2
    constexpr float C2f = 3.6e-3f;   // (0.03*2)^2

    // LDS. hb* are XOR-swizzled (byte ^ ((row&7)<<4)) to spread P3's
    // cross-row b128 reads over banks; wb* rely on pad (66/68) instead.
    __shared__ __align__(16) f32x2 raw[NRAW];        // 12,320 B  (x,y) halo slice
    __shared__ __align__(16) char  hbA[16 * 576];    // f32x2[16][72]  (hx,hy)
    __shared__ __align__(16) char  hbB[16 * 576];    // f32x2[16][72]  (hxx,hyy)
    __shared__ __align__(16) char  hbC[16 * 288];    // float[16][72]  (hxy)
    __shared__ __align__(16) char  wbA[16 * 528];    // f32x2[16][66]
    __shared__ __align__(16) char  wbB[16 * 528];    // f32x2[16][66]
    __shared__ __align__(16) char  wbC[16 * 272];    // float[16][68]
    __shared__ float red[NTH / 64][3];

    const int wt = blockIdx.x, ht = blockIdx.y;
    const int b  = blockIdx.z >> 3, seg = blockIdx.z & 7;
    const int h0 = ht * TH, w0 = wt * TW;
    const int dbase = seg * SEG;
    const long long bbase = (long long)b * (DDIM * HDIM * WDIM);
    const int t = threadIdx.x;

    // ---- P1 invariants: up to 4 raw points per thread (1540 = 3*512 + 4) ----
    int goff[4]; bool ok[4], inter[4];
    #pragma unroll
    for (int i = 0; i < 4; ++i) {
        int idx = (i < 3) ? (t + i * NTH) : (1536 + t);
        const int hh = idx / RWW, ww = idx - hh * RWW;
        const int h = h0 + hh - 3, w = w0 + ww - 3;
        bool o_ = ((unsigned)h < HDIM) && ((unsigned)w < WDIM);
        bool in_ = ((unsigned)(hh - 3) < TH) && ((unsigned)(ww - 3) < TW);
        if (i == 3) { o_ = o_ && (t < 4); in_ = in_ && (t < 4); }
        ok[i] = o_; inter[i] = in_;
        goff[i] = h * WDIM + w;
    }

    // ---- P2 invariants (threads 0..279): 4 H-blur outputs per thread ----
    const int p2iw  = t % RWW;            // 0..69
    const int p2ihg = t / RWW;            // 0..3 when active
    const int p2ih0 = p2ihg * 4;
    const int p2base = p2ih0 * RWW + p2iw;

    // ---- P3 invariants (threads 0..383): 8 W-blur outputs per thread ----
    const int p3q = t & 7, p3rid = t >> 3;
    const int p3plane = p3rid >> 4, p3ih = p3rid & 15;

    // ---- P4 invariants: 2 pixels per thread ----
    const int pw = t & 63, ph0 = t >> 6;  // ph0 in 0..7, second pixel ph0+8

    float ssum = 0.f, l1n = 0.f, l1d = 0.f;
    f32x2 wA[2][7], wB[2][7]; float wC[2][7];
    float pfx[4], pfy[4];

    auto loadslice = [&](int DS) {
        const int d_g = dbase - 3 + DS;
        const bool dok = (unsigned)d_g < (unsigned)DDIM;
        const long long sb = bbase + (long long)d_g * (HDIM * WDIM);
        #pragma unroll
        for (int i = 0; i < 4; ++i) {
            const bool l = dok && ok[i];
            pfx[i] = l ? X[sb + goff[i]] : 0.f;
            pfy[i] = l ? Y[sb + goff[i]] : 0.f;
        }
    };

    auto commit = [&](int ds) {
        raw[t]           = (f32x2){pfx[0], pfy[0]};
        raw[t + NTH]     = (f32x2){pfx[1], pfy[1]};
        raw[t + 2 * NTH] = (f32x2){pfx[2], pfy[2]};
        if (t < 4) raw[1536 + t] = (f32x2){pfx[3], pfy[3]};
        if (ds >= 3 && ds <= SEG + 2) {           // an output D-slice
            #pragma unroll
            for (int i = 0; i < 4; ++i) if (inter[i]) {
                const float xv = pfx[i], yv = pfy[i];
                const float wgt = (yv > -0.9f) ? 5.f : 1.f;
                l1n += wgt * fabsf(xv - yv);
                l1d += wgt;
            }
        }
    };

    auto p2 = [&]() {
        if (t < 280) {
            f32x2 aA[4] = {}; f32x2 aB[4] = {}; float aC[4] = {0.f, 0.f, 0.f, 0.f};
            #pragma unroll
            for (int j = 0; j < 10; ++j) {
                const f32x2 p = raw[p2base + RWW * j];
                const f32x2 sq = p * p;
                const float xyv = p.x * p.y;
                #pragma unroll
                for (int o = 0; o < 4; ++o) {
                    const int k = j - o;
                    if (k >= 0 && k < 7) {
                        const float g = Gc[k];
                        aA[o] += g * p; aB[o] += g * sq; aC[o] += g * xyv;
                    }
                }
            }
            #pragma unroll
            for (int o = 0; o < 4; ++o) {
                const int r = p2ih0 + o;
                const int sw = (r & 7) << 4;
                *(f32x2*)(hbA + ((r * 576 + p2iw * 8) ^ sw)) = aA[o];
                *(f32x2*)(hbB + ((r * 576 + p2iw * 8) ^ sw)) = aB[o];
                *(float*)(hbC + ((r * 288 + p2iw * 4) ^ sw)) = aC[o];
            }
        }
    };

    auto p3 = [&]() {
        if (t < 384) {
            const int ih = p3ih;
            const int sw = (ih & 7) << 4;
            if (p3plane < 2) {
                char* hsrc = p3plane ? hbB : hbA;
                char* wdst = p3plane ? wbB : wbA;
                f32x2 a[8] = {};
                #pragma unroll
                for (int jj = 0; jj < 7; ++jj) {
                    const int off = (ih * 576 + p3q * 64 + jj * 16) ^ sw;
                    const f32x4 v = *(const f32x4*)(hsrc + off);
                    const f32x2 p0 = {v.x, v.y}, p1 = {v.z, v.w};
                    #pragma unroll
                    for (int o = 0; o < 8; ++o) {
                        const int k0 = 2 * jj - o;
                        if (k0 >= 0 && k0 < 7) a[o] += Gc[k0] * p0;
                        const int k1 = 2 * jj + 1 - o;
                        if (k1 >= 0 && k1 < 7) a[o] += Gc[k1] * p1;
                    }
                }
                #pragma unroll
                for (int oo = 0; oo < 8; oo += 2) {
                    const f32x4 s = {a[oo].x, a[oo].y, a[oo + 1].x, a[oo + 1].y};
                    *(f32x4*)(wdst + (ih * 528 + p3q * 64 + oo * 8)) = s;
                }
            } else {
                float a[8] = {};
                #pragma unroll
                for (int jj = 0; jj < 3; ++jj) {
                    const int off = (ih * 288 + p3q * 32 + jj * 16) ^ sw;
                    const f32x4 v = *(const f32x4*)(hbC + off);
                    #pragma unroll
                    for (int u = 0; u < 4; ++u) {
                        const int j = 4 * jj + u;
                        const float vv = (u == 0) ? v.x : (u == 1) ? v.y : (u == 2) ? v.z : v.w;
                        #pragma unroll
                        for (int o = 0; o < 8; ++o) {
                            const int k = j - o;
                            if (k >= 0 && k < 7) a[o] += Gc[k] * vv;
                        }
                    }
                }
                {
                    const int off = (ih * 288 + p3q * 32 + 48) ^ sw;
                    const f32x2 v = *(const f32x2*)(hbC + off);
                    #pragma unroll
                    for (int u = 0; u < 2; ++u) {
                        const int j = 12 + u;
                        const float vv = u ? v.y : v.x;
                        #pragma unroll
                        for (int o = 0; o < 8; ++o) {
                            const int k = j - o;
                            if (k >= 0 && k < 7) a[o] += Gc[k] * vv;
                        }
                    }
                }
                #pragma unroll
                for (int oo = 0; oo < 8; oo += 4) {
                    const f32x4 s = {a[oo], a[oo + 1], a[oo + 2], a[oo + 3]};
                    *(f32x4*)(wbC + (ih * 272 + p3q * 32 + oo * 4)) = s;
                }
            }
        }
    };

    auto phase = [&](auto PPc, int dsb) {
        constexpr int PP = PPc.v;
        const int ds = dsb + PP;
        if (ds < NS) {                       // uniform guard (pad phases no-op)
            commit(ds);
            __syncthreads();
            if (ds + 1 < NS) loadslice(ds + 1);   // overlap with P2/P3/P4
            p2();
            __syncthreads();
            p3();
            __syncthreads();
            // P4: push HW-blurred slice into D-window; emit SSIM when full
            #pragma unroll
            for (int i = 0; i < 2; ++i) {
                const int ph = ph0 + 8 * i;
                const f32x2 av = *(const f32x2*)(wbA + ph * 528 + pw * 8);
                const f32x2 bv = *(const f32x2*)(wbB + ph * 528 + pw * 8);
                const float cv = *(const float*)(wbC + ph * 272 + pw * 4);
                wA[i][PP] = av; wB[i][PP] = bv; wC[i][PP] = cv;
                if (ds >= 6) {
                    f32x2 mu = {0.f, 0.f}, e2 = {0.f, 0.f}; float exy = 0.f;
                    #pragma unroll
                    for (int k = 0; k < 7; ++k) {
                        const int s = (PP + 1 + k) % 7;
                        const float g = Gc[k];
                        mu += g * wA[i][s]; e2 += g * wB[i][s]; exy += g * wC[i][s];
                    }
                    const float mux2 = mu.x * mu.x, muy2 = mu.y * mu.y, muxy = mu.x * mu.y;
                    const float sx2 = e2.x - mux2, sy2 = e2.y - muy2, sxy = exy - muxy;
                    const float num = (2.f * muxy + C1f) * (2.f * sxy + C2f);
                    const float den = (mux2 + muy2 + C1f) * (sx2 + sy2 + C2f);
                    ssum += num * rcp_fast(den);
                }
            }
        }
    };

    loadslice(0);
    for (int it = 0; it < 4; ++it) {
        const int dsb = it * 7;
        phase(IC<0>{}, dsb); phase(IC<1>{}, dsb); phase(IC<2>{}, dsb);
        phase(IC<3>{}, dsb); phase(IC<4>{}, dsb); phase(IC<5>{}, dsb);
        phase(IC<6>{}, dsb);
    }

    // ---- block reduce + atomics ----
    #pragma unroll
    for (int off = 32; off > 0; off >>= 1) {
        ssum += __shfl_down(ssum, off, 64);
        l1n  += __shfl_down(l1n,  off, 64);
        l1d  += __shfl_down(l1d,  off, 64);
    }
    const int wave = t >> 6, lane = t & 63;
    if (lane == 0) { red[wave][0] = ssum; red[wave][1] = l1n; red[wave][2] = l1d; }
    __syncthreads();
    if (t == 0) {
        float s = 0.f, n = 0.f, dn = 0.f;
        #pragma unroll
        for (int i = 0; i < NTH / 64; ++i) {
            s += red[i][0]; n += red[i][1]; dn += red[i][2];
        }
        atomicAdd(&acc[0], s);
        atomicAdd(&acc[1], n);
        atomicAdd(&acc[2], dn);
    }
}

__global__ void nq_final(const float* __restrict__ acc,
                         const float* __restrict__ vq,
                         float* __restrict__ out)
{
    const float ssim_mean = acc[0] / (float)NTOT;
    out[0] = acc[1] / acc[2] + 0.5f * (1.0f - ssim_mean) + vq[0];
}

extern "C" void kernel_launch(void* const* d_in, const int* in_sizes, int n_in,
                              void* d_out, int out_size, void* d_ws, size_t ws_size,
                              hipStream_t stream)
{
    const float* X  = (const float*)d_in[0];  // recon
    const float* Y  = (const float*)d_in[1];  // target
    const float* vq = (const float*)d_in[2];  // scalar
    float* out = (float*)d_out;
    float* acc = (float*)d_ws;

    hipMemsetAsync(acc, 0, 3 * sizeof(float), stream);

    dim3 grid(WDIM / TW, HDIM / TH, BDIM * (DDIM / SEG));   // 3 x 12 x 32
    nq_main<<<grid, NTH, 0, stream>>>(X, Y, acc);
    nq_final<<<1, 1, 0, stream>>>(acc, vq, out);
}

// Round 4
// 308.691 us; speedup vs baseline: 1.2425x; 1.2425x over previous
//
#include <hip/hip_runtime.h>
#include <math.h>

typedef __attribute__((ext_vector_type(2))) float f32x2;
typedef __attribute__((ext_vector_type(4))) float f32x4;

// Problem dims (fixed): (B=4, 1, D=160, H=192, W=192) f32
#define BDIM 4
#define DDIM 160
#define HDIM 192
#define WDIM 192
#define NTOT (BDIM * DDIM * HDIM * WDIM)

#define TH 8
#define TW 64
#define SEG 40               // output D-slices per block
#define NSEG (DDIM / SEG)    // 4
#define NS  (SEG + 6)        // 46 input slices
#define NTH 512

#define RHH (TH + 6)         // 14
#define RWW (TW + 6)         // 70
#define NRAW (RHH * RWW)     // 980

#define HBSTR 72             // hb row stride (elements), 16B-aligned rows

template<int N> struct IC { static constexpr int v = N; };

__device__ __forceinline__ float rcp_fast(float x) {
#if __has_builtin(__builtin_amdgcn_rcpf)
    return __builtin_amdgcn_rcpf(x);
#else
    return 1.0f / x;
#endif
}

__global__ __launch_bounds__(NTH, 6)
void nq_main(const float* __restrict__ X,   // recon
             const float* __restrict__ Y,   // target
             float* __restrict__ acc)       // [0]=ssim_sum [1]=l1_num [2]=l1_den
{
    constexpr float Gc[7] = {
        0.03663285f, 0.11128076f, 0.21674532f, 0.27068215f,
        0.21674532f, 0.11128076f, 0.03663285f };
    constexpr float C1f = 4.0e-4f;   // (0.01*2)^2
    constexpr float C2f = 3.6e-3f;   // (0.03*2)^2

    // ~29.7 KB LDS total -> 3 blocks/CU co-resident (SGPR-capped at 28 waves)
    __shared__ __align__(16) f32x2 raw[NRAW];           //  7,840 B (x,y)
    __shared__ __align__(16) f32x2 hbA[TH][HBSTR];      //  4,608 B (hx,hy)
    __shared__ __align__(16) f32x2 hbB[TH][HBSTR];      //  4,608 B (hxx,hyy)
    __shared__ __align__(16) float hbC[TH][HBSTR];      //  2,304 B (hxy)
    __shared__ __align__(16) f32x2 wbA[TH][TW];         //  4,096 B
    __shared__ __align__(16) f32x2 wbB[TH][TW];         //  4,096 B
    __shared__ __align__(16) float wbC[TH][TW];         //  2,048 B
    __shared__ float red[NTH / 64][3];

    const int wt  = blockIdx.x;            // 0..2
    const int ht  = blockIdx.y;            // 0..23
    const int b   = blockIdx.z >> 2;       // 0..3
    const int seg = blockIdx.z & 3;        // 0..3
    const int h0 = ht * TH, w0 = wt * TW;
    const int dbase = seg * SEG;
    const long long bbase = (long long)b * (DDIM * HDIM * WDIM);
    const int t = threadIdx.x;

    // ---- P1 invariants: 2 raw points/thread (980 = 512 + 468) ----
    int goff[2]; bool ok[2], inter[2];
    #pragma unroll
    for (int i = 0; i < 2; ++i) {
        const int idx = t + i * NTH;
        const int hh = idx / RWW, ww = idx - hh * RWW;
        const int h = h0 + hh - 3, w = w0 + ww - 3;
        bool o_ = ((unsigned)h < HDIM) && ((unsigned)w < WDIM);
        bool in_ = ((unsigned)(hh - 3) < TH) && ((unsigned)(ww - 3) < TW);
        if (i == 1 && idx >= NRAW) { o_ = false; in_ = false; }
        ok[i] = o_; inter[i] = in_;
        goff[i] = h * WDIM + w;
    }
    const bool has1 = (t + NTH) < NRAW;    // t < 468

    // ---- P2 invariants: H-blur items (560 = 512 + 48) ----
    const int p2r0 = t / RWW, p2w0 = t - p2r0 * RWW;               // pass 1
    const int p2r1 = (t + NTH) / RWW, p2w1 = (t + NTH) - p2r1 * RWW; // pass 2 (t<48)
    const bool p2has1 = (t + NTH) < TH * RWW;

    // ---- P3 invariants: W-blur, 4 outputs/thread, 384 items ----
    const int p3p = t >> 7;                // plane 0=A 1=B 2=C
    const int p3r = (t >> 4) & 7;          // row
    const int p3q = t & 15;                // quad of output cols
    const bool p3act = t < 384;

    // ---- P4 invariants: 1 pixel/thread ----
    const int pw = t & 63, ph = t >> 6;

    float ssum = 0.f, l1n = 0.f, l1d = 0.f;
    f32x2 wA[7], wB[7]; float wC[7];       // D-window, statically rotated
    float pfx[2], pfy[2];

    auto loadslice = [&](int DS) {
        const int d_g = dbase - 3 + DS;
        const bool dok = (unsigned)d_g < (unsigned)DDIM;
        const long long sb = bbase + (long long)d_g * (HDIM * WDIM);
        #pragma unroll
        for (int i = 0; i < 2; ++i) {
            const bool l = dok && ok[i];
            pfx[i] = l ? X[sb + goff[i]] : 0.f;
            pfy[i] = l ? Y[sb + goff[i]] : 0.f;
        }
    };

    auto commit = [&](int ds) {
        raw[t] = (f32x2){pfx[0], pfy[0]};
        if (has1) raw[t + NTH] = (f32x2){pfx[1], pfy[1]};
        if (ds >= 3 && ds <= SEG + 2) {
            #pragma unroll
            for (int i = 0; i < 2; ++i) if (inter[i]) {
                const float wgt = (pfy[i] > -0.9f) ? 5.f : 1.f;
                l1n += wgt * fabsf(pfx[i] - pfy[i]);
                l1d += wgt;
            }
        }
    };

    auto p2item = [&](int r, int w) {
        f32x2 aA = {0.f, 0.f}, aB = {0.f, 0.f}; float aC = 0.f;
        #pragma unroll
        for (int k = 0; k < 7; ++k) {
            const f32x2 p = raw[(r + k) * RWW + w];
            const float g = Gc[k];
            aA += g * p;
            aB += (g * p) * p;
            aC += g * (p.x * p.y);
        }
        hbA[r][w] = aA; hbB[r][w] = aB; hbC[r][w] = aC;
    };

    auto p3pk = [&](const f32x2 (*src)[HBSTR], f32x2 (*dst)[TW], int r, int q) {
        // 4 outputs (cols 4q..4q+3) from 10 input cols (4q..4q+9)
        const f32x2* row = &src[r][0];
        f32x2 v[10];
        #pragma unroll
        for (int j = 0; j < 5; ++j) {
            const f32x4 x4 = *(const f32x4*)(row + 4 * q + 2 * j);
            v[2 * j]     = (f32x2){x4.x, x4.y};
            v[2 * j + 1] = (f32x2){x4.z, x4.w};
        }
        #pragma unroll
        for (int o = 0; o < 4; o += 2) {
            f32x2 a0 = {0.f, 0.f}, a1 = {0.f, 0.f};
            #pragma unroll
            for (int k = 0; k < 7; ++k) {
                a0 += Gc[k] * v[o + k];
                a1 += Gc[k] * v[o + 1 + k];
            }
            *(f32x4*)(&dst[r][4 * q + o]) = (f32x4){a0.x, a0.y, a1.x, a1.y};
        }
    };

    auto p3sc = [&](int r, int q) {
        const float* row = &hbC[r][0];
        float v[10];
        #pragma unroll
        for (int j = 0; j < 2; ++j) {
            const f32x4 x4 = *(const f32x4*)(row + 4 * q + 4 * j);
            v[4 * j] = x4.x; v[4 * j + 1] = x4.y; v[4 * j + 2] = x4.z; v[4 * j + 3] = x4.w;
        }
        const f32x2 x2 = *(const f32x2*)(row + 4 * q + 8);
        v[8] = x2.x; v[9] = x2.y;
        float o[4];
        #pragma unroll
        for (int j = 0; j < 4; ++j) {
            float a = 0.f;
            #pragma unroll
            for (int k = 0; k < 7; ++k) a += Gc[k] * v[j + k];
            o[j] = a;
        }
        *(f32x4*)(&wbC[r][4 * q]) = (f32x4){o[0], o[1], o[2], o[3]};
    };

    auto phase = [&](auto PPc, int dsb) {
        constexpr int PP = PPc.v;
        const int ds = dsb + PP;
        if (ds < NS) {
            commit(ds);
            __syncthreads();
            if (ds + 1 < NS) loadslice(ds + 1);   // overlap next-slice HBM fetch
            // P2: H-blur raw -> hb
            p2item(p2r0, p2w0);
            if (p2has1) p2item(p2r1, p2w1);
            __syncthreads();
            // P3: W-blur hb -> wb
            if (p3act) {
                if (p3p == 0)      p3pk(hbA, wbA, p3r, p3q);
                else if (p3p == 1) p3pk(hbB, wbB, p3r, p3q);
                else               p3sc(p3r, p3q);
            }
            __syncthreads();
            // P4: push into D-window (static slot PP); emit SSIM when full
            wA[PP] = wbA[ph][pw];
            wB[PP] = wbB[ph][pw];
            wC[PP] = wbC[ph][pw];
            if (ds >= 6) {
                f32x2 mu = {0.f, 0.f}, e2 = {0.f, 0.f}; float exy = 0.f;
                #pragma unroll
                for (int k = 0; k < 7; ++k) {
                    const int s = (PP + 1 + k) % 7;
                    const float g = Gc[k];
                    mu += g * wA[s]; e2 += g * wB[s]; exy += g * wC[s];
                }
                const float mux2 = mu.x * mu.x, muy2 = mu.y * mu.y, muxy = mu.x * mu.y;
                const float sx2 = e2.x - mux2, sy2 = e2.y - muy2, sxy = exy - muxy;
                const float num = (2.f * muxy + C1f) * (2.f * sxy + C2f);
                const float den = (mux2 + muy2 + C1f) * (sx2 + sy2 + C2f);
                ssum += num * rcp_fast(den);
            }
        }
    };

    loadslice(0);
    for (int it = 0; it < 7; ++it) {       // 7*7 = 49 slots, guard ds < 46
        const int dsb = it * 7;
        phase(IC<0>{}, dsb); phase(IC<1>{}, dsb); phase(IC<2>{}, dsb);
        phase(IC<3>{}, dsb); phase(IC<4>{}, dsb); phase(IC<5>{}, dsb);
        phase(IC<6>{}, dsb);
    }

    // ---- block reduce + atomics ----
    #pragma unroll
    for (int off = 32; off > 0; off >>= 1) {
        ssum += __shfl_down(ssum, off, 64);
        l1n  += __shfl_down(l1n,  off, 64);
        l1d  += __shfl_down(l1d,  off, 64);
    }
    const int wave = t >> 6, lane = t & 63;
    if (lane == 0) { red[wave][0] = ssum; red[wave][1] = l1n; red[wave][2] = l1d; }
    __syncthreads();
    if (t == 0) {
        float s = 0.f, n = 0.f, dn = 0.f;
        #pragma unroll
        for (int i = 0; i < NTH / 64; ++i) {
            s += red[i][0]; n += red[i][1]; dn += red[i][2];
        }
        atomicAdd(&acc[0], s);
        atomicAdd(&acc[1], n);
        atomicAdd(&acc[2], dn);
    }
}

__global__ void nq_final(const float* __restrict__ acc,
                         const float* __restrict__ vq,
                         float* __restrict__ out)
{
    const float ssim_mean = acc[0] / (float)NTOT;
    out[0] = acc[1] / acc[2] + 0.5f * (1.0f - ssim_mean) + vq[0];
}

extern "C" void kernel_launch(void* const* d_in, const int* in_sizes, int n_in,
                              void* d_out, int out_size, void* d_ws, size_t ws_size,
                              hipStream_t stream)
{
    const float* X  = (const float*)d_in[0];  // recon
    const float* Y  = (const float*)d_in[1];  // target
    const float* vq = (const float*)d_in[2];  // scalar
    float* out = (float*)d_out;
    float* acc = (float*)d_ws;

    hipMemsetAsync(acc, 0, 3 * sizeof(float), stream);

    dim3 grid(WDIM / TW, HDIM / TH, BDIM * NSEG);   // 3 x 24 x 16 = 1152 blocks
    nq_main<<<grid, NTH, 0, stream>>>(X, Y, acc);
    nq_final<<<1, 1, 0, stream>>>(acc, vq, out);
}

// Round 5
// 171.920 us; speedup vs baseline: 2.2310x; 1.7956x over previous
//
#include <hip/hip_runtime.h>
#include <math.h>

typedef __attribute__((ext_vector_type(2))) float f32x2;
typedef __attribute__((ext_vector_type(4))) float f32x4;

// Problem dims (fixed): (B=4, 1, D=160, H=192, W=192) f32
#define BDIM 4
#define DDIM 160
#define HDIM 192
#define WDIM 192
#define NTOT (BDIM * DDIM * HDIM * WDIM)

#define TH 8
#define TW 64
#define SEG 20               // output D-slices per block
#define NSEG (DDIM / SEG)    // 8
#define NS  (SEG + 6)        // 26 input slices
#define NSTEP (NS + 2)       // 28 pipeline steps = 4 x 7 exactly
#define NTH 512

#define RHH (TH + 6)         // 14
#define RWW (TW + 6)         // 70
#define NRAW (RHH * RWW)     // 980

#define HBSTR 72             // hb row stride (elements), 16B-aligned rows

template<int N> struct IC { static constexpr int v = N; };

__device__ __forceinline__ float rcp_fast(float x) {
#if __has_builtin(__builtin_amdgcn_rcpf)
    return __builtin_amdgcn_rcpf(x);
#else
    return 1.0f / x;
#endif
}

__global__ __launch_bounds__(NTH, 4)
void nq_main(const float* __restrict__ X,   // recon
             const float* __restrict__ Y,   // target
             float* __restrict__ acc)       // [0]=ssim_sum [1]=l1_num [2]=l1_den
{
    constexpr float Gc[7] = {
        0.03663285f, 0.11128076f, 0.21674532f, 0.27068215f,
        0.21674532f, 0.11128076f, 0.03663285f };
    constexpr float C1f = 4.0e-4f;   // (0.01*2)^2
    constexpr float C2f = 3.6e-3f;   // (0.03*2)^2

    // Double-buffered systolic pipeline: ~59.3 KB -> 2 blocks/CU.
    __shared__ __align__(16) f32x2 raw[2][NRAW];        // 15,680 B (x,y)
    __shared__ __align__(16) f32x2 hbA[2][TH][HBSTR];   //  9,216 B (hx,hy)
    __shared__ __align__(16) f32x2 hbB[2][TH][HBSTR];   //  9,216 B (hxx,hyy)
    __shared__ __align__(16) float hbC[2][TH][HBSTR];   //  4,608 B (hxy)
    __shared__ __align__(16) f32x2 wbA[2][TH][TW];      //  8,192 B
    __shared__ __align__(16) f32x2 wbB[2][TH][TW];      //  8,192 B
    __shared__ __align__(16) float wbC[2][TH][TW];      //  4,096 B
    __shared__ float red[NTH / 64][3];

    const int wt  = blockIdx.x;            // 0..2
    const int ht  = blockIdx.y;            // 0..23
    const int b   = blockIdx.z >> 3;       // 0..3
    const int seg = blockIdx.z & 7;        // 0..7
    const int h0 = ht * TH, w0 = wt * TW;
    const int dbase = seg * SEG;
    const long long bbase = (long long)b * (DDIM * HDIM * WDIM);
    const int t = threadIdx.x;

    // ---- commit/load invariants: 2 raw points/thread (980 = 512 + 468) ----
    int goff[2]; bool ok[2], inter[2];
    #pragma unroll
    for (int i = 0; i < 2; ++i) {
        const int idx = t + i * NTH;
        const int hh = idx / RWW, ww = idx - hh * RWW;
        const int h = h0 + hh - 3, w = w0 + ww - 3;
        bool o_ = ((unsigned)h < HDIM) && ((unsigned)w < WDIM);
        bool in_ = ((unsigned)(hh - 3) < TH) && ((unsigned)(ww - 3) < TW);
        if (i == 1 && idx >= NRAW) { o_ = false; in_ = false; }
        ok[i] = o_; inter[i] = in_;
        goff[i] = h * WDIM + w;
    }
    const bool has1 = (t + NTH) < NRAW;    // t < 468

    // ---- P2 invariants: H-blur items (560 = 512 + 48) ----
    const int p2r0 = t / RWW, p2w0 = t - p2r0 * RWW;
    const int p2r1 = (t + NTH) / RWW, p2w1 = (t + NTH) - p2r1 * RWW;
    const bool p2has1 = (t + NTH) < TH * RWW;

    // ---- P3 invariants: W-blur, 4 outputs/thread, 384 items ----
    const int p3p = t >> 7;                // plane 0=A 1=B 2=C
    const int p3r = (t >> 4) & 7;          // row
    const int p3q = t & 15;                // quad of output cols
    const bool p3act = t < 384;

    // ---- P4 invariants: 1 pixel/thread ----
    const int pw = t & 63, ph = t >> 6;

    float ssum = 0.f, l1n = 0.f, l1d = 0.f;
    f32x2 wA[7], wB[7]; float wC[7];       // D-window, statically rotated
    float pfx[2], pfy[2];

    auto loadslice = [&](int s) {          // prefetch raw slice s into regs
        const int d_g = dbase - 3 + s;
        const bool dok = (unsigned)d_g < (unsigned)DDIM;
        const long long sb = bbase + (long long)d_g * (HDIM * WDIM);
        #pragma unroll
        for (int i = 0; i < 2; ++i) {
            const bool l = dok && ok[i];
            pfx[i] = l ? X[sb + goff[i]] : 0.f;
            pfy[i] = l ? Y[sb + goff[i]] : 0.f;
        }
    };

    auto commit = [&](int s) {             // write prefetched slice s to LDS (+L1)
        const int rb = s & 1;
        raw[rb][t] = (f32x2){pfx[0], pfy[0]};
        if (has1) raw[rb][t + NTH] = (f32x2){pfx[1], pfy[1]};
        if (s >= 3 && s <= SEG + 2) {
            #pragma unroll
            for (int i = 0; i < 2; ++i) if (inter[i]) {
                const float wgt = (pfy[i] > -0.9f) ? 5.f : 1.f;
                l1n += wgt * fabsf(pfx[i] - pfy[i]);
                l1d += wgt;
            }
        }
    };

    auto p2item = [&](int rb, int r, int w) {
        f32x2 aA = {0.f, 0.f}, aB = {0.f, 0.f}; float aC = 0.f;
        #pragma unroll
        for (int k = 0; k < 7; ++k) {
            const f32x2 p = raw[rb][(r + k) * RWW + w];
            const float g = Gc[k];
            aA += g * p;
            aB += (g * p) * p;
            aC += g * (p.x * p.y);
        }
        hbA[rb][r][w] = aA; hbB[rb][r][w] = aB; hbC[rb][r][w] = aC;
    };

    auto p3pk = [&](const f32x2 (*src)[HBSTR], f32x2 (*dst)[TW], int r, int q) {
        const f32x2* row = &src[r][0];
        f32x2 v[10];
        #pragma unroll
        for (int j = 0; j < 5; ++j) {
            const f32x4 x4 = *(const f32x4*)(row + 4 * q + 2 * j);
            v[2 * j]     = (f32x2){x4.x, x4.y};
            v[2 * j + 1] = (f32x2){x4.z, x4.w};
        }
        #pragma unroll
        for (int o = 0; o < 4; o += 2) {
            f32x2 a0 = {0.f, 0.f}, a1 = {0.f, 0.f};
            #pragma unroll
            for (int k = 0; k < 7; ++k) {
                a0 += Gc[k] * v[o + k];
                a1 += Gc[k] * v[o + 1 + k];
            }
            *(f32x4*)(&dst[r][4 * q + o]) = (f32x4){a0.x, a0.y, a1.x, a1.y};
        }
    };

    auto p3sc = [&](const float (*srcC)[HBSTR], float (*dstC)[TW], int r, int q) {
        const float* row = &srcC[r][0];
        float v[10];
        #pragma unroll
        for (int j = 0; j < 2; ++j) {
            const f32x4 x4 = *(const f32x4*)(row + 4 * q + 4 * j);
            v[4 * j] = x4.x; v[4 * j + 1] = x4.y; v[4 * j + 2] = x4.z; v[4 * j + 3] = x4.w;
        }
        const f32x2 x2 = *(const f32x2*)(row + 4 * q + 8);
        v[8] = x2.x; v[9] = x2.y;
        float o[4];
        #pragma unroll
        for (int j = 0; j < 4; ++j) {
            float a = 0.f;
            #pragma unroll
            for (int k = 0; k < 7; ++k) a += Gc[k] * v[j + k];
            o[j] = a;
        }
        *(f32x4*)(&dstC[r][4 * q]) = (f32x4){o[0], o[1], o[2], o[3]};
    };

    // step ps: commit slice ps+1; prefetch ps+2; P2 slice ps; P3 slice ps-1;
    // P4 pushes slice ps-2 (window slot = (ps-2+2)%7 = ps%7 = PP, static);
    // emits output od = ps-8 when ps >= 8. ONE barrier at end of step.
    auto phase = [&](auto PPc, int it) {
        constexpr int PP = PPc.v;
        const int ps = it * 7 + PP;
        const int par = ps & 1;

        if (ps <= NS - 2) commit(ps + 1);            // -> raw[(ps+1)&1]
        if (ps <= NS - 3) loadslice(ps + 2);         // regs, lands during compute

        if (ps <= NS - 1) {                          // P2: raw[ps&1] -> hb[ps&1]
            p2item(par, p2r0, p2w0);
            if (p2has1) p2item(par, p2r1, p2w1);
        }
        if (ps >= 1 && ps <= NS) {                   // P3: hb[(ps-1)&1] -> wb[(ps-1)&1]
            const int hp = par ^ 1;
            if (p3act) {
                if (p3p == 0)      p3pk(hbA[hp], wbA[hp], p3r, p3q);
                else if (p3p == 1) p3pk(hbB[hp], wbB[hp], p3r, p3q);
                else               p3sc(hbC[hp], wbC[hp], p3r, p3q);
            }
        }
        if (ps >= 2) {                               // P4: wb[(ps-2)&1] = wb[par]
            wA[PP] = wbA[par][ph][pw];
            wB[PP] = wbB[par][ph][pw];
            wC[PP] = wbC[par][ph][pw];
            if (ps >= 8) {
                f32x2 mu = {0.f, 0.f}, e2 = {0.f, 0.f}; float exy = 0.f;
                #pragma unroll
                for (int k = 0; k < 7; ++k) {
                    const int s = (PP + 1 + k) % 7;
                    const float g = Gc[k];
                    mu += g * wA[s]; e2 += g * wB[s]; exy += g * wC[s];
                }
                const float mux2 = mu.x * mu.x, muy2 = mu.y * mu.y, muxy = mu.x * mu.y;
                const float sx2 = e2.x - mux2, sy2 = e2.y - muy2, sxy = exy - muxy;
                const float num = (2.f * muxy + C1f) * (2.f * sxy + C2f);
                const float den = (mux2 + muy2 + C1f) * (sx2 + sy2 + C2f);
                ssum += num * rcp_fast(den);
            }
        }
        __syncthreads();
    };

    // prologue: slice 0 committed, slice 1 prefetched
    loadslice(0);
    commit(0);
    loadslice(1);
    __syncthreads();

    for (int it = 0; it < 4; ++it) {       // 28 steps exactly
        phase(IC<0>{}, it); phase(IC<1>{}, it); phase(IC<2>{}, it);
        phase(IC<3>{}, it); phase(IC<4>{}, it); phase(IC<5>{}, it);
        phase(IC<6>{}, it);
    }

    // ---- block reduce + atomics ----
    #pragma unroll
    for (int off = 32; off > 0; off >>= 1) {
        ssum += __shfl_down(ssum, off, 64);
        l1n  += __shfl_down(l1n,  off, 64);
        l1d  += __shfl_down(l1d,  off, 64);
    }
    const int wave = t >> 6, lane = t & 63;
    if (lane == 0) { red[wave][0] = ssum; red[wave][1] = l1n; red[wave][2] = l1d; }
    __syncthreads();
    if (t == 0) {
        float s = 0.f, n = 0.f, dn = 0.f;
        #pragma unroll
        for (int i = 0; i < NTH / 64; ++i) {
            s += red[i][0]; n += red[i][1]; dn += red[i][2];
        }
        atomicAdd(&acc[0], s);
        atomicAdd(&acc[1], n);
        atomicAdd(&acc[2], dn);
    }
}

__global__ void nq_final(const float* __restrict__ acc,
                         const float* __restrict__ vq,
                         float* __restrict__ out)
{
    const float ssim_mean = acc[0] / (float)NTOT;
    out[0] = acc[1] / acc[2] + 0.5f * (1.0f - ssim_mean) + vq[0];
}

extern "C" void kernel_launch(void* const* d_in, const int* in_sizes, int n_in,
                              void* d_out, int out_size, void* d_ws, size_t ws_size,
                              hipStream_t stream)
{
    const float* X  = (const float*)d_in[0];  // recon
    const float* Y  = (const float*)d_in[1];  // target
    const float* vq = (const float*)d_in[2];  // scalar
    float* out = (float*)d_out;
    float* acc = (float*)d_ws;

    hipMemsetAsync(acc, 0, 3 * sizeof(float), stream);

    dim3 grid(WDIM / TW, HDIM / TH, BDIM * NSEG);   // 3 x 24 x 32 = 2304 blocks
    nq_main<<<grid, NTH, 0, stream>>>(X, Y, acc);
    nq_final<<<1, 1, 0, stream>>>(acc, vq, out);
}